// Round 13
// baseline (387.042 us; speedup 1.0000x reference)
//
#include <hip/hip_runtime.h>
#include <hip/hip_bf16.h>

// B=2, C=256 (nh=8, hd=32), H=W=64, HW=4096.
// dw3x3(fp32->bf16) -> pw1x1 bf16 MFMA -> flash attn bf16 MFMA 32x32x16.
// attn: 64 q/wave, 8-wave blocks (8-way K-split), wave-private single-buffered
// LDS slab, barrier-free main loop, O^T orientation (sums/O lane-local per q).
// Occupancy play: 8192 waves, launch_bounds(512,6) -> 24-32 waves/CU.

#define HW 4096
#define CDIM 256
#define SCALE_LOG2E 0.2550348543f  // (1/sqrt(32)) * log2(e)

typedef short bf16x8 __attribute__((ext_vector_type(8)));
typedef float f32x2 __attribute__((ext_vector_type(2)));
typedef float f32x4 __attribute__((ext_vector_type(4)));
typedef float f32x16 __attribute__((ext_vector_type(16)));

__device__ inline unsigned short f2bf(float f) {  // RNE bf16
  unsigned u = __float_as_uint(f);
  u = (u + 0x7fffu + ((u >> 16) & 1u)) >> 16;
  return (unsigned short)u;
}

__device__ inline unsigned cvtpk(float lo, float hi) {  // 2xf32 -> packed bf16
  unsigned r;
  asm("v_cvt_pk_bf16_f32 %0, %1, %2" : "=v"(r) : "v"(lo), "v"(hi));
  return r;
}

__device__ inline float fexp2(float x) {
#if __has_builtin(__builtin_amdgcn_exp2f)
  return __builtin_amdgcn_exp2f(x);
#else
  return exp2f(x);
#endif
}

// permlane32_swap: a' = [a.lo, b.lo], b' = [a.hi, b.hi]
__device__ inline void plswap(unsigned& a, unsigned& b) {
#if __has_builtin(__builtin_amdgcn_permlane32_swap)
  auto r = __builtin_amdgcn_permlane32_swap((int)a, (int)b, false, false);
  a = (unsigned)r[0];
  b = (unsigned)r[1];
#else
  unsigned as = __shfl_xor((int)a, 32), bs = __shfl_xor((int)b, 32);
  bool hi = (threadIdx.x & 32) != 0;
  unsigned na = hi ? bs : a;
  unsigned nb = hi ? b : as;
  a = na; b = nb;
#endif
}

// ---------------- depthwise 3x3 + bias; pass0: x->tq, pass1: ctx->{tk,tv} ----------------
__global__ __launch_bounds__(256) void dw_all(
    const float* __restrict__ x, const float* __restrict__ ctx,
    const float* __restrict__ qdw, const float* __restrict__ qdwb,
    const float* __restrict__ kdw, const float* __restrict__ kdwb,
    const float* __restrict__ vdw, const float* __restrict__ vdwb,
    unsigned short* __restrict__ tq, unsigned short* __restrict__ tk,
    unsigned short* __restrict__ tv) {
  int gid = blockIdx.x * 256 + threadIdx.x;
  int pass = gid >> 19;
  int r = gid & 524287;
  int q4 = r & 1023;
  int plane = r >> 10;
  int c = plane & 255;
  int w0 = (q4 & 15) * 4, h = q4 >> 4;
  const float* src = (pass ? ctx : x) + (size_t)plane * HW;

  float e[3][6];
#pragma unroll
  for (int kh = 0; kh < 3; ++kh) {
    int hh = h + kh - 1;
    if (hh < 0 || hh > 63) {
#pragma unroll
      for (int j = 0; j < 6; ++j) e[kh][j] = 0.f;
    } else {
      const float* row = src + hh * 64 + w0;
      float4 m = *(const float4*)row;
      e[kh][0] = (w0 > 0) ? row[-1] : 0.f;
      e[kh][1] = m.x; e[kh][2] = m.y; e[kh][3] = m.z; e[kh][4] = m.w;
      e[kh][5] = (w0 < 60) ? row[4] : 0.f;
    }
  }
  size_t obase = (size_t)plane * HW + h * 64 + w0;
  if (pass == 0) {
    const float* wc = qdw + c * 9;
    float bv = qdwb[c];
    float a0 = bv, a1 = bv, a2 = bv, a3 = bv;
#pragma unroll
    for (int kh = 0; kh < 3; ++kh) {
      float w_0 = wc[kh * 3], w_1 = wc[kh * 3 + 1], w_2 = wc[kh * 3 + 2];
      a0 += w_0 * e[kh][0] + w_1 * e[kh][1] + w_2 * e[kh][2];
      a1 += w_0 * e[kh][1] + w_1 * e[kh][2] + w_2 * e[kh][3];
      a2 += w_0 * e[kh][2] + w_1 * e[kh][3] + w_2 * e[kh][4];
      a3 += w_0 * e[kh][3] + w_1 * e[kh][4] + w_2 * e[kh][5];
    }
    *(ushort4*)(tq + obase) = make_ushort4(f2bf(a0), f2bf(a1), f2bf(a2), f2bf(a3));
  } else {
    const float* wk = kdw + c * 9;
    const float* wvv = vdw + c * 9;
    float bk = kdwb[c], bv2 = vdwb[c];
    float k0 = bk, k1 = bk, k2 = bk, k3 = bk;
    float v0 = bv2, v1 = bv2, v2 = bv2, v3 = bv2;
#pragma unroll
    for (int kh = 0; kh < 3; ++kh) {
      float kw0 = wk[kh * 3], kw1 = wk[kh * 3 + 1], kw2 = wk[kh * 3 + 2];
      float vw0 = wvv[kh * 3], vw1 = wvv[kh * 3 + 1], vw2 = wvv[kh * 3 + 2];
      k0 += kw0 * e[kh][0] + kw1 * e[kh][1] + kw2 * e[kh][2];
      k1 += kw0 * e[kh][1] + kw1 * e[kh][2] + kw2 * e[kh][3];
      k2 += kw0 * e[kh][2] + kw1 * e[kh][3] + kw2 * e[kh][4];
      k3 += kw0 * e[kh][3] + kw1 * e[kh][4] + kw2 * e[kh][5];
      v0 += vw0 * e[kh][0] + vw1 * e[kh][1] + vw2 * e[kh][2];
      v1 += vw0 * e[kh][1] + vw1 * e[kh][2] + vw2 * e[kh][3];
      v2 += vw0 * e[kh][2] + vw1 * e[kh][3] + vw2 * e[kh][4];
      v3 += vw0 * e[kh][3] + vw1 * e[kh][4] + vw2 * e[kh][5];
    }
    *(ushort4*)(tk + obase) = make_ushort4(f2bf(k0), f2bf(k1), f2bf(k2), f2bf(k3));
    *(ushort4*)(tv + obase) = make_ushort4(f2bf(v0), f2bf(v1), f2bf(v2), f2bf(v3));
  }
}

// ---------------- pointwise 1x1 bf16 MFMA (all 3 tensors) ----------------
__global__ __launch_bounds__(256) void pw_all(
    const unsigned short* __restrict__ tq, const unsigned short* __restrict__ tk,
    const unsigned short* __restrict__ tv,
    const float* __restrict__ qw, const float* __restrict__ qbs,
    const float* __restrict__ kw, const float* __restrict__ kbs,
    const float* __restrict__ vw, const float* __restrict__ vbs,
    unsigned short* __restrict__ Qc, unsigned short* __restrict__ Kc,
    unsigned short* __restrict__ Vc) {
  __shared__ __align__(16) unsigned char Bs[64 * 512];
  int tt = blockIdx.x >> 9;
  int bid = blockIdx.x & 511;
  const unsigned short* t = tt == 0 ? tq : (tt == 1 ? tk : tv);
  const float* w = tt == 0 ? qw : (tt == 1 ? kw : vw);
  const float* bias = tt == 0 ? qbs : (tt == 1 ? kbs : vbs);
  unsigned short* out = tt == 0 ? Qc : (tt == 1 ? Kc : Vc);
  float oscale = tt == 0 ? SCALE_LOG2E : 1.0f;

  int pt = bid & 63, cot = (bid >> 6) & 3, bb = bid >> 8;
  int p0 = pt * 64, co0 = cot * 64;
  int tid = threadIdx.x;
  int wv = tid >> 6, l = tid & 63, lq = l & 15, lg = l >> 4;

  bf16x8 af[8];
  {
    const float* wr = w + (size_t)(co0 + wv * 16 + lq) * 256;
#pragma unroll
    for (int kt = 0; kt < 8; ++kt) {
      float4 a = *(const float4*)(wr + kt * 32 + lg * 8);
      float4 bq = *(const float4*)(wr + kt * 32 + lg * 8 + 4);
      union { unsigned u[4]; bf16x8 v; } cv;
      cv.u[0] = cvtpk(a.x, a.y);  cv.u[1] = cvtpk(a.z, a.w);
      cv.u[2] = cvtpk(bq.x, bq.y); cv.u[3] = cvtpk(bq.z, bq.w);
      af[kt] = cv.v;
    }
  }
  {
    int cb = tid >> 3, po = tid & 7;
    const unsigned short* src = t + (size_t)bb * (CDIM * HW) + (size_t)(cb * 8) * HW + p0 + po * 8;
    uint4 r[8];
#pragma unroll
    for (int i = 0; i < 8; ++i) r[i] = *(const uint4*)(src + (size_t)i * HW);
#pragma unroll
    for (int jj = 0; jj < 8; ++jj) {
      uint4 o;
#pragma unroll
      for (int ww = 0; ww < 4; ++ww) {
        unsigned a = ((const unsigned*)&r[2 * ww])[jj >> 1];
        unsigned b = ((const unsigned*)&r[2 * ww + 1])[jj >> 1];
        unsigned lo = (jj & 1) ? (a >> 16) : (a & 0xffffu);
        unsigned hi = (jj & 1) ? (b & 0xffff0000u) : (b << 16);
        (&o.x)[ww] = lo | hi;
      }
      int p = po * 8 + jj;
      int swz = ((p ^ (p >> 3)) & 7) << 4;
      *(uint4*)(Bs + p * 512 + ((cb * 16) ^ swz)) = o;
    }
  }
  __syncthreads();
  f32x4 acc[4] = {};
#pragma unroll
  for (int nt = 0; nt < 4; ++nt) {
    int p = nt * 16 + lq;
    int swz = ((p ^ (p >> 3)) & 7) << 4;
    const unsigned char* Bp = Bs + p * 512;
#pragma unroll
    for (int kt = 0; kt < 8; ++kt) {
      bf16x8 bf = *(const bf16x8*)(Bp + ((kt * 64 + lg * 16) ^ swz));
      acc[nt] = __builtin_amdgcn_mfma_f32_16x16x32_bf16(af[kt], bf, acc[nt], 0, 0, 0);
    }
  }
  if (tt < 2) {
    int co = co0 + wv * 16 + lg * 4;
    int d0 = co & 31;
    float b0 = bias[co], b1 = bias[co + 1], b2 = bias[co + 2], b3 = bias[co + 3];
    size_t rowb = (size_t)(bb * 8 + (co >> 5)) * HW;
#pragma unroll
    for (int nt = 0; nt < 4; ++nt) {
      int p = p0 + nt * 16 + lq;
      ushort4 pk = make_ushort4(f2bf((acc[nt][0] + b0) * oscale),
                                f2bf((acc[nt][1] + b1) * oscale),
                                f2bf((acc[nt][2] + b2) * oscale),
                                f2bf((acc[nt][3] + b3) * oscale));
      *(ushort4*)(out + (rowb + p) * 32 + d0) = pk;
    }
  } else {
    int cob = co0 + wv * 16 + lg * 4;
#pragma unroll
    for (int r = 0; r < 4; ++r) {
      float bv = bias[cob + r];
      size_t rb = (size_t)bb * (CDIM * HW) + (size_t)(cob + r) * HW + p0;
#pragma unroll
      for (int nt = 0; nt < 4; ++nt)
        out[rb + nt * 16 + lq] = f2bf(acc[nt][r] + bv);
    }
  }
}

// ---------------- MFMA flash attention: 8 waves, 8-way K-split ----------------
// grid 1024 (16 bh x 64 qb), 512 thr (8 waves). Wave = ks eighth (512 kpos),
// 64 q (2 subtiles), chunk = 32 kpos, 16 chunks. Wave-private 5KB slab
// (K 32x80 + V 32x80), single-buffered, barrier-free loop (per-wave DS order).
// Merge: 3-round LDS tree across the 8 ks waves (exact: no-max softmax).
__global__ __launch_bounds__(512, 6) void attn_kernel(
    const unsigned short* __restrict__ Qt, const unsigned short* __restrict__ Kt,
    const unsigned short* __restrict__ Vn, float* __restrict__ out) {
  __shared__ __align__(16) unsigned char lds[40960];
  int bid0 = blockIdx.x;
  int bid = (bid0 & 7) * 128 + (bid0 >> 3);  // XCD swizzle (1024 % 8 == 0)
  int qb = bid & 63, bh = bid >> 6;
  int b = bh >> 3, n = bh & 7;
  int tid = threadIdx.x;
  int l = tid & 63, ks = tid >> 6;       // ks = 0..7
  int lq = l & 31, hi = l >> 5;

  const unsigned short* Qg = Qt + (size_t)bh * (HW * 32);
  const unsigned short* Kg = Kt + (size_t)bh * (HW * 32);
  const unsigned short* Vg = Vn + (size_t)(b * CDIM + n * 32) * HW;

  int q0 = qb * 64;
  bf16x8 qa0 = *(const bf16x8*)(Qg + (size_t)(q0 + lq) * 32 + hi * 8);
  bf16x8 qa1 = *(const bf16x8*)(Qg + (size_t)(q0 + lq) * 32 + 16 + hi * 8);
  bf16x8 qB0 = *(const bf16x8*)(Qg + (size_t)(q0 + 32 + lq) * 32 + hi * 8);
  bf16x8 qB1 = *(const bf16x8*)(Qg + (size_t)(q0 + 32 + lq) * 32 + 16 + hi * 8);

  f32x16 Oa = {}, Ob = {}, ZZ = {};
  float psa = 0.f, psb = 0.f;

  // wave-private slab: K @ +0 (32 rows x 80B), V @ +2560 (32 rows x 80B)
  unsigned char* Kl = lds + ks * 5120;
  unsigned char* Vl = Kl + 2560;
  unsigned char* Kw0 = Kl + (l >> 2) * 80 + (l & 3) * 16;   // rows 0-15
  unsigned char* Kw1 = Kw0 + 16 * 80;                        // rows 16-31
  unsigned char* Vw0 = Vl + (l >> 2) * 80 + (l & 3) * 16;
  unsigned char* Vw1 = Vw0 + 16 * 80;
  const uint4* Ks4 = (const uint4*)Kg + (size_t)ks * 2048;   // ks*512 kpos * 32e /8
  const unsigned short* Vs0 = Vg + (size_t)(l >> 2) * HW + ks * 512 + (l & 3) * 8;
  const unsigned short* Vs1 = Vs0 + (size_t)16 * HW;

  // prologue: chunk 0 -> slab
  {
    uint4 gk0 = Ks4[l], gk1 = Ks4[64 + l];
    uint4 gv0 = *(const uint4*)Vs0, gv1 = *(const uint4*)Vs1;
    *(uint4*)Kw0 = gk0; *(uint4*)Kw1 = gk1;
    *(uint4*)Vw0 = gv0; *(uint4*)Vw1 = gv1;
  }

  const unsigned char* Kr = Kl + lq * 80 + hi * 16;  // A-frag K: row=kpos, k=d
  const unsigned char* Vr = Vl + lq * 80 + hi * 16;  // A-frag V: row=d, k=kpos

  auto subtile = [&](bf16x8 kfa, bf16x8 kfb, bf16x8 va, bf16x8 vb,
                     bf16x8 qf0, bf16x8 qf1, f32x16& O, float& ps) {
    __builtin_amdgcn_s_setprio(1);
    f32x16 st = __builtin_amdgcn_mfma_f32_32x32x16_bf16(kfa, qf0, ZZ, 0, 0, 0);
    st = __builtin_amdgcn_mfma_f32_32x32x16_bf16(kfb, qf1, st, 0, 0, 0);
    __builtin_amdgcn_s_setprio(0);
    float p[16];
#pragma unroll
    for (int r = 0; r < 16; ++r) p[r] = fexp2(st[r]);
    f32x2 s0 = (f32x2){p[0], p[1]} + (f32x2){p[2], p[3]};
    f32x2 s1 = (f32x2){p[4], p[5]} + (f32x2){p[6], p[7]};
    f32x2 s2 = (f32x2){p[8], p[9]} + (f32x2){p[10], p[11]};
    f32x2 s3 = (f32x2){p[12], p[13]} + (f32x2){p[14], p[15]};
    f32x2 s4 = (s0 + s1) + (s2 + s3);
    ps += s4[0] + s4[1];
    unsigned u0 = cvtpk(p[0], p[1]),  u1 = cvtpk(p[2], p[3]);
    unsigned u2 = cvtpk(p[4], p[5]),  u3 = cvtpk(p[6], p[7]);
    unsigned u4 = cvtpk(p[8], p[9]),  u5 = cvtpk(p[10], p[11]);
    unsigned u6 = cvtpk(p[12], p[13]), u7 = cvtpk(p[14], p[15]);
    plswap(u0, u2);
    plswap(u1, u3);
    plswap(u4, u6);
    plswap(u5, u7);
    union { unsigned w[4]; bf16x8 v; } X1, X2;
    X1.w[0] = u0; X1.w[1] = u1; X1.w[2] = u2; X1.w[3] = u3;
    X2.w[0] = u4; X2.w[1] = u5; X2.w[2] = u6; X2.w[3] = u7;
    __builtin_amdgcn_s_setprio(1);
    O = __builtin_amdgcn_mfma_f32_32x32x16_bf16(va, X1.v, O, 0, 0, 0);
    O = __builtin_amdgcn_mfma_f32_32x32x16_bf16(vb, X2.v, O, 0, 0, 0);
    __builtin_amdgcn_s_setprio(0);
  };

#pragma unroll 1
  for (int c = 0; c < 16; ++c) {
    bf16x8 kfa = *(const bf16x8*)(Kr);
    bf16x8 kfb = *(const bf16x8*)(Kr + 32);
    bf16x8 va  = *(const bf16x8*)(Vr);
    bf16x8 vb  = *(const bf16x8*)(Vr + 32);
    subtile(kfa, kfb, va, vb, qa0, qa1, Oa, psa);
    subtile(kfa, kfb, va, vb, qB0, qB1, Ob, psb);
    if (c < 15) {  // short-lived staging: load then immediately commit to slab
      uint4 gk0 = Ks4[(c + 1) * 128 + l];
      uint4 gk1 = Ks4[(c + 1) * 128 + 64 + l];
      uint4 gv0 = *(const uint4*)(Vs0 + (c + 1) * 32);
      uint4 gv1 = *(const uint4*)(Vs1 + (c + 1) * 32);
      *(uint4*)Kw0 = gk0; *(uint4*)Kw1 = gk1;
      *(uint4*)Vw0 = gv0; *(uint4*)Vw1 = gv1;
    }
  }

  // ---- 8-way ks merge (exact adds; O and ps lane-local per q) ----
  psa += __shfl_xor(psa, 32);
  psb += __shfl_xor(psb, 32);
  __syncthreads();
  float* MO = (float*)lds;                 // 4 slots x [2 sub][32 d][33]
  float* MS = (float*)(lds + 33792);       // 4 slots x [psa 32 | psb 32]
  const int SLOT = 2112, SUB = 1056;

  auto stash = [&](int s) {
#pragma unroll
    for (int r = 0; r < 16; ++r) {
      int d = (r & 3) + 8 * (r >> 2) + 4 * hi;
      MO[s * SLOT + d * 33 + lq] = Oa[r];
      MO[s * SLOT + SUB + d * 33 + lq] = Ob[r];
    }
    if (hi == 0) { MS[s * 64 + lq] = psa; MS[s * 64 + 32 + lq] = psb; }
  };
  auto accum = [&](int s) {
#pragma unroll
    for (int r = 0; r < 16; ++r) {
      int d = (r & 3) + 8 * (r >> 2) + 4 * hi;
      Oa[r] += MO[s * SLOT + d * 33 + lq];
      Ob[r] += MO[s * SLOT + SUB + d * 33 + lq];
    }
    psa += MS[s * 64 + lq];
    psb += MS[s * 64 + 32 + lq];
  };

  if (ks & 1) stash(ks >> 1);
  __syncthreads();
  if (!(ks & 1)) accum(ks >> 1);
  __syncthreads();
  if (ks == 2) stash(0);
  if (ks == 6) stash(1);
  __syncthreads();
  if (ks == 0) accum(0);
  if (ks == 4) accum(1);
  __syncthreads();
  if (ks == 4) stash(0);
  __syncthreads();
  if (ks == 0) {
    accum(0);
    float rva = 1.0f / psa;
    float rvb = 1.0f / psb;
    size_t ob = ((size_t)(b * CDIM) + n * 32) * HW;
#pragma unroll
    for (int r = 0; r < 16; ++r) {
      int d = (r & 3) + 8 * (r >> 2) + 4 * hi;
      out[ob + (size_t)d * HW + q0 + lq] = Oa[r] * rva;
      out[ob + (size_t)d * HW + q0 + 32 + lq] = Ob[r] * rvb;
    }
  }
}

extern "C" void kernel_launch(void* const* d_in, const int* in_sizes, int n_in,
                              void* d_out, int out_size, void* d_ws, size_t ws_size,
                              hipStream_t stream) {
  const float* x   = (const float*)d_in[0];
  const float* ctx = (const float*)d_in[1];
  const float* q_dw  = (const float*)d_in[2];
  const float* q_dwb = (const float*)d_in[3];
  const float* q_pw  = (const float*)d_in[4];
  const float* q_pwb = (const float*)d_in[5];
  const float* k_dw  = (const float*)d_in[6];
  const float* k_dwb = (const float*)d_in[7];
  const float* k_pw  = (const float*)d_in[8];
  const float* k_pwb = (const float*)d_in[9];
  const float* v_dw  = (const float*)d_in[10];
  const float* v_dwb = (const float*)d_in[11];
  const float* v_pw  = (const float*)d_in[12];
  const float* v_pwb = (const float*)d_in[13];

  const size_t N = (size_t)2 * CDIM * HW;
  unsigned short* Qc = (unsigned short*)d_ws;       // ws: Qc,Kc,Vc,tv (16MB)
  unsigned short* Kc = Qc + N;
  unsigned short* Vc = Kc + N;
  unsigned short* tv = Vc + N;
  unsigned short* tq = (unsigned short*)d_out;      // d_out hosts tq+tk (8MB)
  unsigned short* tk = tq + N;

  dw_all<<<4096, 256, 0, stream>>>(x, ctx, q_dw, q_dwb, k_dw, k_dwb, v_dw, v_dwb,
                                   tq, tk, tv);
  pw_all<<<1536, 256, 0, stream>>>(tq, tk, tv, q_pw, q_pwb, k_pw, k_pwb,
                                   v_pw, v_pwb, Qc, Kc, Vc);
  attn_kernel<<<1024, 512, 0, stream>>>(Qc, Kc, Vc, (float*)d_out);
}

// Round 14
// 86.637 us; speedup vs baseline: 4.4674x; 4.4674x over previous
//
#include <hip/hip_runtime.h>
#include <hip/hip_bf16.h>

// B=2, C=256 (nh=8, hd=32), H=W=64, HW=4096.
// dw3x3(fp32->bf16) -> pw1x1 bf16 MFMA -> flash attn bf16 MFMA 32x32x16.
// attn: 64 q/wave, 4-way K-split, NO LDS STAGING — K/V fragments loaded
// directly from global (L2-resident via XCD swizzle), depth-2 reg prefetch.
// O^T orientation (PV = mfma(V, P)): sums/O lane-local per q. LDS = merge only.

#define HW 4096
#define CDIM 256
#define SCALE_LOG2E 0.2550348543f  // (1/sqrt(32)) * log2(e)

typedef short bf16x8 __attribute__((ext_vector_type(8)));
typedef float f32x2 __attribute__((ext_vector_type(2)));
typedef float f32x4 __attribute__((ext_vector_type(4)));
typedef float f32x16 __attribute__((ext_vector_type(16)));

__device__ inline unsigned short f2bf(float f) {  // RNE bf16
  unsigned u = __float_as_uint(f);
  u = (u + 0x7fffu + ((u >> 16) & 1u)) >> 16;
  return (unsigned short)u;
}

__device__ inline unsigned cvtpk(float lo, float hi) {  // 2xf32 -> packed bf16
  unsigned r;
  asm("v_cvt_pk_bf16_f32 %0, %1, %2" : "=v"(r) : "v"(lo), "v"(hi));
  return r;
}

__device__ inline float fexp2(float x) {
#if __has_builtin(__builtin_amdgcn_exp2f)
  return __builtin_amdgcn_exp2f(x);
#else
  return exp2f(x);
#endif
}

// permlane32_swap: a' = [a.lo, b.lo], b' = [a.hi, b.hi]
__device__ inline void plswap(unsigned& a, unsigned& b) {
#if __has_builtin(__builtin_amdgcn_permlane32_swap)
  auto r = __builtin_amdgcn_permlane32_swap((int)a, (int)b, false, false);
  a = (unsigned)r[0];
  b = (unsigned)r[1];
#else
  unsigned as = __shfl_xor((int)a, 32), bs = __shfl_xor((int)b, 32);
  bool hi = (threadIdx.x & 32) != 0;
  unsigned na = hi ? bs : a;
  unsigned nb = hi ? b : as;
  a = na; b = nb;
#endif
}

// ---------------- depthwise 3x3 + bias; pass0: x->tq, pass1: ctx->{tk,tv} ----------------
__global__ __launch_bounds__(256) void dw_all(
    const float* __restrict__ x, const float* __restrict__ ctx,
    const float* __restrict__ qdw, const float* __restrict__ qdwb,
    const float* __restrict__ kdw, const float* __restrict__ kdwb,
    const float* __restrict__ vdw, const float* __restrict__ vdwb,
    unsigned short* __restrict__ tq, unsigned short* __restrict__ tk,
    unsigned short* __restrict__ tv) {
  int gid = blockIdx.x * 256 + threadIdx.x;
  int pass = gid >> 19;
  int r = gid & 524287;
  int q4 = r & 1023;
  int plane = r >> 10;
  int c = plane & 255;
  int w0 = (q4 & 15) * 4, h = q4 >> 4;
  const float* src = (pass ? ctx : x) + (size_t)plane * HW;

  float e[3][6];
#pragma unroll
  for (int kh = 0; kh < 3; ++kh) {
    int hh = h + kh - 1;
    if (hh < 0 || hh > 63) {
#pragma unroll
      for (int j = 0; j < 6; ++j) e[kh][j] = 0.f;
    } else {
      const float* row = src + hh * 64 + w0;
      float4 m = *(const float4*)row;
      e[kh][0] = (w0 > 0) ? row[-1] : 0.f;
      e[kh][1] = m.x; e[kh][2] = m.y; e[kh][3] = m.z; e[kh][4] = m.w;
      e[kh][5] = (w0 < 60) ? row[4] : 0.f;
    }
  }
  size_t obase = (size_t)plane * HW + h * 64 + w0;
  if (pass == 0) {
    const float* wc = qdw + c * 9;
    float bv = qdwb[c];
    float a0 = bv, a1 = bv, a2 = bv, a3 = bv;
#pragma unroll
    for (int kh = 0; kh < 3; ++kh) {
      float w_0 = wc[kh * 3], w_1 = wc[kh * 3 + 1], w_2 = wc[kh * 3 + 2];
      a0 += w_0 * e[kh][0] + w_1 * e[kh][1] + w_2 * e[kh][2];
      a1 += w_0 * e[kh][1] + w_1 * e[kh][2] + w_2 * e[kh][3];
      a2 += w_0 * e[kh][2] + w_1 * e[kh][3] + w_2 * e[kh][4];
      a3 += w_0 * e[kh][3] + w_1 * e[kh][4] + w_2 * e[kh][5];
    }
    *(ushort4*)(tq + obase) = make_ushort4(f2bf(a0), f2bf(a1), f2bf(a2), f2bf(a3));
  } else {
    const float* wk = kdw + c * 9;
    const float* wvv = vdw + c * 9;
    float bk = kdwb[c], bv2 = vdwb[c];
    float k0 = bk, k1 = bk, k2 = bk, k3 = bk;
    float v0 = bv2, v1 = bv2, v2 = bv2, v3 = bv2;
#pragma unroll
    for (int kh = 0; kh < 3; ++kh) {
      float kw0 = wk[kh * 3], kw1 = wk[kh * 3 + 1], kw2 = wk[kh * 3 + 2];
      float vw0 = wvv[kh * 3], vw1 = wvv[kh * 3 + 1], vw2 = wvv[kh * 3 + 2];
      k0 += kw0 * e[kh][0] + kw1 * e[kh][1] + kw2 * e[kh][2];
      k1 += kw0 * e[kh][1] + kw1 * e[kh][2] + kw2 * e[kh][3];
      k2 += kw0 * e[kh][2] + kw1 * e[kh][3] + kw2 * e[kh][4];
      k3 += kw0 * e[kh][3] + kw1 * e[kh][4] + kw2 * e[kh][5];
      v0 += vw0 * e[kh][0] + vw1 * e[kh][1] + vw2 * e[kh][2];
      v1 += vw0 * e[kh][1] + vw1 * e[kh][2] + vw2 * e[kh][3];
      v2 += vw0 * e[kh][2] + vw1 * e[kh][3] + vw2 * e[kh][4];
      v3 += vw0 * e[kh][3] + vw1 * e[kh][4] + vw2 * e[kh][5];
    }
    *(ushort4*)(tk + obase) = make_ushort4(f2bf(k0), f2bf(k1), f2bf(k2), f2bf(k3));
    *(ushort4*)(tv + obase) = make_ushort4(f2bf(v0), f2bf(v1), f2bf(v2), f2bf(v3));
  }
}

// ---------------- pointwise 1x1 bf16 MFMA (all 3 tensors) ----------------
__global__ __launch_bounds__(256) void pw_all(
    const unsigned short* __restrict__ tq, const unsigned short* __restrict__ tk,
    const unsigned short* __restrict__ tv,
    const float* __restrict__ qw, const float* __restrict__ qbs,
    const float* __restrict__ kw, const float* __restrict__ kbs,
    const float* __restrict__ vw, const float* __restrict__ vbs,
    unsigned short* __restrict__ Qc, unsigned short* __restrict__ Kc,
    unsigned short* __restrict__ Vc) {
  __shared__ __align__(16) unsigned char Bs[64 * 512];
  int tt = blockIdx.x >> 9;
  int bid = blockIdx.x & 511;
  const unsigned short* t = tt == 0 ? tq : (tt == 1 ? tk : tv);
  const float* w = tt == 0 ? qw : (tt == 1 ? kw : vw);
  const float* bias = tt == 0 ? qbs : (tt == 1 ? kbs : vbs);
  unsigned short* out = tt == 0 ? Qc : (tt == 1 ? Kc : Vc);
  float oscale = tt == 0 ? SCALE_LOG2E : 1.0f;

  int pt = bid & 63, cot = (bid >> 6) & 3, bb = bid >> 8;
  int p0 = pt * 64, co0 = cot * 64;
  int tid = threadIdx.x;
  int wv = tid >> 6, l = tid & 63, lq = l & 15, lg = l >> 4;

  bf16x8 af[8];
  {
    const float* wr = w + (size_t)(co0 + wv * 16 + lq) * 256;
#pragma unroll
    for (int kt = 0; kt < 8; ++kt) {
      float4 a = *(const float4*)(wr + kt * 32 + lg * 8);
      float4 bq = *(const float4*)(wr + kt * 32 + lg * 8 + 4);
      union { unsigned u[4]; bf16x8 v; } cv;
      cv.u[0] = cvtpk(a.x, a.y);  cv.u[1] = cvtpk(a.z, a.w);
      cv.u[2] = cvtpk(bq.x, bq.y); cv.u[3] = cvtpk(bq.z, bq.w);
      af[kt] = cv.v;
    }
  }
  {
    int cb = tid >> 3, po = tid & 7;
    const unsigned short* src = t + (size_t)bb * (CDIM * HW) + (size_t)(cb * 8) * HW + p0 + po * 8;
    uint4 r[8];
#pragma unroll
    for (int i = 0; i < 8; ++i) r[i] = *(const uint4*)(src + (size_t)i * HW);
#pragma unroll
    for (int jj = 0; jj < 8; ++jj) {
      uint4 o;
#pragma unroll
      for (int ww = 0; ww < 4; ++ww) {
        unsigned a = ((const unsigned*)&r[2 * ww])[jj >> 1];
        unsigned b = ((const unsigned*)&r[2 * ww + 1])[jj >> 1];
        unsigned lo = (jj & 1) ? (a >> 16) : (a & 0xffffu);
        unsigned hi = (jj & 1) ? (b & 0xffff0000u) : (b << 16);
        (&o.x)[ww] = lo | hi;
      }
      int p = po * 8 + jj;
      int swz = ((p ^ (p >> 3)) & 7) << 4;
      *(uint4*)(Bs + p * 512 + ((cb * 16) ^ swz)) = o;
    }
  }
  __syncthreads();
  f32x4 acc[4] = {};
#pragma unroll
  for (int nt = 0; nt < 4; ++nt) {
    int p = nt * 16 + lq;
    int swz = ((p ^ (p >> 3)) & 7) << 4;
    const unsigned char* Bp = Bs + p * 512;
#pragma unroll
    for (int kt = 0; kt < 8; ++kt) {
      bf16x8 bf = *(const bf16x8*)(Bp + ((kt * 64 + lg * 16) ^ swz));
      acc[nt] = __builtin_amdgcn_mfma_f32_16x16x32_bf16(af[kt], bf, acc[nt], 0, 0, 0);
    }
  }
  if (tt < 2) {
    int co = co0 + wv * 16 + lg * 4;
    int d0 = co & 31;
    float b0 = bias[co], b1 = bias[co + 1], b2 = bias[co + 2], b3 = bias[co + 3];
    size_t rowb = (size_t)(bb * 8 + (co >> 5)) * HW;
#pragma unroll
    for (int nt = 0; nt < 4; ++nt) {
      int p = p0 + nt * 16 + lq;
      ushort4 pk = make_ushort4(f2bf((acc[nt][0] + b0) * oscale),
                                f2bf((acc[nt][1] + b1) * oscale),
                                f2bf((acc[nt][2] + b2) * oscale),
                                f2bf((acc[nt][3] + b3) * oscale));
      *(ushort4*)(out + (rowb + p) * 32 + d0) = pk;
    }
  } else {
    int cob = co0 + wv * 16 + lg * 4;
#pragma unroll
    for (int r = 0; r < 4; ++r) {
      float bv = bias[cob + r];
      size_t rb = (size_t)bb * (CDIM * HW) + (size_t)(cob + r) * HW + p0;
#pragma unroll
      for (int nt = 0; nt < 4; ++nt)
        out[rb + nt * 16 + lq] = f2bf(acc[nt][r] + bv);
    }
  }
}

// ---------------- MFMA flash attention: direct-global frags, no LDS staging ----------------
// grid 1024 (16 bh x 64 qb), 256 thr (4 waves). Wave = ks quarter (1024 kpos),
// 64 q (2 subtiles), chunk = 32 kpos. K frag: coalesced 16B/lane from Kt[pos][32].
// V frag: 16B/lane rows of Vc[d][pos] (full 64B line used per chunk).
// Depth-2 named prefetch (A/B sets). XCD swizzle -> each XCD owns 2 bh (L2-res).
__global__ __launch_bounds__(256, 3) void attn_kernel(
    const unsigned short* __restrict__ Qt, const unsigned short* __restrict__ Kt,
    const unsigned short* __restrict__ Vn, float* __restrict__ out) {
  __shared__ __align__(16) float MOS[4736];  // merge overlay: MO 4224 + MS 512
  int bid0 = blockIdx.x;
  int bid = (bid0 & 7) * 128 + (bid0 >> 3);  // XCD swizzle (1024 % 8 == 0)
  int qb = bid & 63, bh = bid >> 6;
  int b = bh >> 3, n = bh & 7;
  int tid = threadIdx.x;
  int l = tid & 63, ks = tid >> 6;
  int lq = l & 31, hi = l >> 5;

  const unsigned short* Qg = Qt + (size_t)bh * (HW * 32);
  const unsigned short* Kg = Kt + (size_t)bh * (HW * 32);
  const unsigned short* Vg = Vn + (size_t)(b * CDIM + n * 32) * HW;

  int q0 = qb * 64;
  bf16x8 qa0 = *(const bf16x8*)(Qg + (size_t)(q0 + lq) * 32 + hi * 8);
  bf16x8 qa1 = *(const bf16x8*)(Qg + (size_t)(q0 + lq) * 32 + 16 + hi * 8);
  bf16x8 qB0 = *(const bf16x8*)(Qg + (size_t)(q0 + 32 + lq) * 32 + hi * 8);
  bf16x8 qB1 = *(const bf16x8*)(Qg + (size_t)(q0 + 32 + lq) * 32 + 16 + hi * 8);

  f32x16 Oa = {}, Ob = {}, ZZ = {};
  float psa = 0.f, psb = 0.f;

  // per-lane frag source pointers (chunk c advances by 32 kpos)
  const unsigned short* Kp = Kg + (size_t)(ks * 1024 + lq) * 32 + hi * 8;  // + c*32*32
  const unsigned short* Vp = Vg + (size_t)lq * HW + ks * 1024 + hi * 8;    // + c*32

  auto loadF = [&](int c, bf16x8& ka, bf16x8& kb, bf16x8& va, bf16x8& vb) {
    const unsigned short* kp = Kp + (size_t)c * 1024;  // 32 pos * 32 elem
    ka = *(const bf16x8*)(kp);        // d 0..15 (per-hi 8)
    kb = *(const bf16x8*)(kp + 16);   // d 16..31
    const unsigned short* vp = Vp + c * 32;
    va = *(const bf16x8*)(vp);        // kpos_local 0..15
    vb = *(const bf16x8*)(vp + 16);   // kpos_local 16..31
  };

  auto subtile = [&](bf16x8 kfa, bf16x8 kfb, bf16x8 va, bf16x8 vb,
                     bf16x8 qf0, bf16x8 qf1, f32x16& O, float& ps) {
    __builtin_amdgcn_s_setprio(1);
    f32x16 st = __builtin_amdgcn_mfma_f32_32x32x16_bf16(kfa, qf0, ZZ, 0, 0, 0);
    st = __builtin_amdgcn_mfma_f32_32x32x16_bf16(kfb, qf1, st, 0, 0, 0);
    __builtin_amdgcn_s_setprio(0);
    float p[16];
#pragma unroll
    for (int r = 0; r < 16; ++r) p[r] = fexp2(st[r]);
    f32x2 s0 = (f32x2){p[0], p[1]} + (f32x2){p[2], p[3]};
    f32x2 s1 = (f32x2){p[4], p[5]} + (f32x2){p[6], p[7]};
    f32x2 s2 = (f32x2){p[8], p[9]} + (f32x2){p[10], p[11]};
    f32x2 s3 = (f32x2){p[12], p[13]} + (f32x2){p[14], p[15]};
    f32x2 s4 = (s0 + s1) + (s2 + s3);
    ps += s4[0] + s4[1];
    unsigned u0 = cvtpk(p[0], p[1]),  u1 = cvtpk(p[2], p[3]);
    unsigned u2 = cvtpk(p[4], p[5]),  u3 = cvtpk(p[6], p[7]);
    unsigned u4 = cvtpk(p[8], p[9]),  u5 = cvtpk(p[10], p[11]);
    unsigned u6 = cvtpk(p[12], p[13]), u7 = cvtpk(p[14], p[15]);
    plswap(u0, u2);
    plswap(u1, u3);
    plswap(u4, u6);
    plswap(u5, u7);
    union { unsigned w[4]; bf16x8 v; } X1, X2;
    X1.w[0] = u0; X1.w[1] = u1; X1.w[2] = u2; X1.w[3] = u3;
    X2.w[0] = u4; X2.w[1] = u5; X2.w[2] = u6; X2.w[3] = u7;
    __builtin_amdgcn_s_setprio(1);
    O = __builtin_amdgcn_mfma_f32_32x32x16_bf16(va, X1.v, O, 0, 0, 0);
    O = __builtin_amdgcn_mfma_f32_32x32x16_bf16(vb, X2.v, O, 0, 0, 0);
    __builtin_amdgcn_s_setprio(0);
  };

  bf16x8 kaA, kbA, vaA, vbA, kaB, kbB, vaB, vbB;
  loadF(0, kaA, kbA, vaA, vbA);
  loadF(1, kaB, kbB, vaB, vbB);

#pragma unroll 1
  for (int c = 0; c < 32; c += 2) {
    subtile(kaA, kbA, vaA, vbA, qa0, qa1, Oa, psa);
    subtile(kaA, kbA, vaA, vbA, qB0, qB1, Ob, psb);
    if (c + 2 < 32) loadF(c + 2, kaA, kbA, vaA, vbA);
    subtile(kaB, kbB, vaB, vbB, qa0, qa1, Oa, psa);
    subtile(kaB, kbB, vaB, vbB, qB0, qB1, Ob, psb);
    if (c + 3 < 32) loadF(c + 3, kaB, kbB, vaB, vbB);
  }

  // ---- ks merge (exact: no-max softmax => plain adds). O lane-local per q. ----
  psa += __shfl_xor(psa, 32);
  psb += __shfl_xor(psb, 32);
  __syncthreads();
  float* MO = MOS;                 // [2 set][2 sub][32 d][33]
  float* MS = MOS + 4224;          // [2 set][2 sub][32 q]
  const int SET = 2112, SUB = 1056;

  if (ks == 1 || ks == 3) {
    int s = (ks == 3);
#pragma unroll
    for (int r = 0; r < 16; ++r) {
      int d = (r & 3) + 8 * (r >> 2) + 4 * hi;
      MO[s * SET + d * 33 + lq] = Oa[r];
      MO[s * SET + SUB + d * 33 + lq] = Ob[r];
    }
    if (hi == 0) {
      MS[s * 128 + lq] = psa;
      MS[s * 128 + 32 + lq] = psb;
    }
  }
  __syncthreads();
  if (ks == 0 || ks == 2) {
    int s = (ks == 2);
#pragma unroll
    for (int r = 0; r < 16; ++r) {
      int d = (r & 3) + 8 * (r >> 2) + 4 * hi;
      Oa[r] += MO[s * SET + d * 33 + lq];
      Ob[r] += MO[s * SET + SUB + d * 33 + lq];
    }
    psa += MS[s * 128 + lq];
    psb += MS[s * 128 + 32 + lq];
  }
  __syncthreads();
  if (ks == 2) {
#pragma unroll
    for (int r = 0; r < 16; ++r) {
      int d = (r & 3) + 8 * (r >> 2) + 4 * hi;
      MO[d * 33 + lq] = Oa[r];
      MO[SUB + d * 33 + lq] = Ob[r];
    }
    if (hi == 0) {
      MS[lq] = psa;
      MS[32 + lq] = psb;
    }
  }
  __syncthreads();
  if (ks == 0) {
#pragma unroll
    for (int r = 0; r < 16; ++r) {
      int d = (r & 3) + 8 * (r >> 2) + 4 * hi;
      Oa[r] += MO[d * 33 + lq];
      Ob[r] += MO[SUB + d * 33 + lq];
    }
    float rva = 1.0f / (psa + MS[lq]);
    float rvb = 1.0f / (psb + MS[32 + lq]);
    size_t ob = ((size_t)(b * CDIM) + n * 32) * HW;
#pragma unroll
    for (int r = 0; r < 16; ++r) {
      int d = (r & 3) + 8 * (r >> 2) + 4 * hi;
      out[ob + (size_t)d * HW + q0 + lq] = Oa[r] * rva;
      out[ob + (size_t)d * HW + q0 + 32 + lq] = Ob[r] * rvb;
    }
  }
}

extern "C" void kernel_launch(void* const* d_in, const int* in_sizes, int n_in,
                              void* d_out, int out_size, void* d_ws, size_t ws_size,
                              hipStream_t stream) {
  const float* x   = (const float*)d_in[0];
  const float* ctx = (const float*)d_in[1];
  const float* q_dw  = (const float*)d_in[2];
  const float* q_dwb = (const float*)d_in[3];
  const float* q_pw  = (const float*)d_in[4];
  const float* q_pwb = (const float*)d_in[5];
  const float* k_dw  = (const float*)d_in[6];
  const float* k_dwb = (const float*)d_in[7];
  const float* k_pw  = (const float*)d_in[8];
  const float* k_pwb = (const float*)d_in[9];
  const float* v_dw  = (const float*)d_in[10];
  const float* v_dwb = (const float*)d_in[11];
  const float* v_pw  = (const float*)d_in[12];
  const float* v_pwb = (const float*)d_in[13];

  const size_t N = (size_t)2 * CDIM * HW;
  unsigned short* Qc = (unsigned short*)d_ws;       // ws: Qc,Kc,Vc,tv (16MB)
  unsigned short* Kc = Qc + N;
  unsigned short* Vc = Kc + N;
  unsigned short* tv = Vc + N;
  unsigned short* tq = (unsigned short*)d_out;      // d_out hosts tq+tk (8MB)
  unsigned short* tk = tq + N;

  dw_all<<<4096, 256, 0, stream>>>(x, ctx, q_dw, q_dwb, k_dw, k_dwb, v_dw, v_dwb,
                                   tq, tk, tv);
  pw_all<<<1536, 256, 0, stream>>>(tq, tk, tv, q_pw, q_pwb, k_pw, k_pwb,
                                   v_pw, v_pwb, Qc, Kc, Vc);
  attn_kernel<<<1024, 256, 0, stream>>>(Qc, Kc, Vc, (float*)d_out);
}